// Round 4
// baseline (525.602 us; speedup 1.0000x reference)
//
#include <hip/hip_runtime.h>

// ---------------------------------------------------------------------------
// DifferentiableTreeDense: out[b, l*128+o] =
//    leaf_prob[b,l] * (dot(x[b,:], leaf_w[l,:,o]) + bias[l,o])
//
// R4: (1) A(kt+1) fully staged in P1 (max slack before end-of-tile vmcnt);
//     (2) epilogue stores ni-innermost (256B contiguous merge window);
//     (3) routing_gemm + leafprob fused (logits never leave LDS).
// ---------------------------------------------------------------------------

typedef __attribute__((ext_vector_type(8))) short short8;
typedef __attribute__((ext_vector_type(4))) float f32x4;

#define BATCH 8192
#define FEAT  1024
#define NLEAF 64
#define LEAFD 128
#define OUTD  8192

#define BM 256
#define BN 256
#define BK 64
#define NT (FEAT / BK)   // 16 K-tiles

__device__ __forceinline__ unsigned short f2bf(float f) {
    union { float f; unsigned int u; } c; c.f = f;
    unsigned int u = c.u;
    return (unsigned short)((u + 0x7FFFu + ((u >> 16) & 1u)) >> 16);  // RNE
}

__device__ __forceinline__ void gload16(const void* g, void* l) {
    // async global->LDS, 16B per lane. LDS dest must be wave-uniform base + lane*16.
    __builtin_amdgcn_global_load_lds(
        (const __attribute__((address_space(1))) unsigned int*)g,
        (__attribute__((address_space(3))) unsigned int*)l, 16, 0, 0);
}

// --------------------------- conversion kernels ----------------------------

__global__ __launch_bounds__(256) void cvt_x(const float* __restrict__ x,
                                             unsigned short* __restrict__ xb) {
    const int i = (blockIdx.x * 256 + threadIdx.x) * 4;
    const float4 v = *(const float4*)(x + i);
    ushort4 o;
    o.x = f2bf(v.x); o.y = f2bf(v.y); o.z = f2bf(v.z); o.w = f2bf(v.w);
    *(ushort4*)(xb + i) = o;
}

// leaf_weights fp32 [64][1024][128] -> bf16 transposed [64][128][1024]
__global__ __launch_bounds__(256) void cvt_lw(const float* __restrict__ lw,
                                              unsigned short* __restrict__ wt) {
    __shared__ float tile[32][33];
    const int l  = blockIdx.x;
    const int k0 = blockIdx.y * 32;
    const int o0 = blockIdx.z * 32;
    const int tr = threadIdx.x >> 5;
    const int tc = threadIdx.x & 31;
    const float* src = lw + (size_t)l * (FEAT * LEAFD);
#pragma unroll
    for (int p = 0; p < 4; ++p) {
        const int r = p * 8 + tr;
        tile[r][tc] = src[(size_t)(k0 + r) * LEAFD + o0 + tc];
    }
    __syncthreads();
    unsigned short* dst = wt + (size_t)l * (LEAFD * FEAT);
#pragma unroll
    for (int p = 0; p < 4; ++p) {
        const int oo = p * 8 + tr;
        dst[(size_t)(o0 + oo) * FEAT + k0 + tc] = f2bf(tile[tc][oo]);
    }
}

__global__ __launch_bounds__(256) void cvt_rw(const float* __restrict__ rw,
                                              unsigned short* __restrict__ rt) {
    const int gid = blockIdx.x * 256 + threadIdx.x;
    const int row = gid >> 10;
    const int f   = gid & 1023;
    const float v = (row < 126) ? rw[(size_t)(row >> 1) * 2048 + f * 2 + (row & 1)] : 0.0f;
    rt[gid] = f2bf(v);
}

// -------------------- fused routing GEMM + leaf probs ----------------------
// Per block: 128 batch rows. logits[128][128] computed into LDS (never hits
// global), then lp[b][leaf] = prod_d sigmoid(z_dir - z_other) written out.
__global__ __launch_bounds__(256) void routing_lp(
        const unsigned short* __restrict__ xb,
        const unsigned short* __restrict__ rt,
        const int* __restrict__ pn,          // [64][6]
        const int* __restrict__ pd,          // [64][6]
        float* __restrict__ lp) {            // [8192][64]
    __shared__ __align__(16) unsigned short As[128 * 32];
    __shared__ __align__(16) unsigned short Bs[128 * 32];
    __shared__ float lg[128][130];           // logits + pad (bank spread)
    __shared__ int pnl[NLEAF * 6], pdl[NLEAF * 6];

    const int t    = threadIdx.x;
    const int row0 = blockIdx.x * 128;
    const int wv = t >> 6, ln = t & 63;
    const int wm = wv >> 1, wn = wv & 1;
    const int quad = ln >> 4, r16 = ln & 15;

    // path tables -> LDS (384 ints)
    if (t < NLEAF * 6) { pnl[t] = pn[t]; pdl[t] = pd[t]; }
    if (t + 256 < NLEAF * 6) { pnl[t + 256] = pn[t + 256]; pdl[t + 256] = pd[t + 256]; }

    f32x4 acc[4][4];
#pragma unroll
    for (int i = 0; i < 4; ++i)
#pragma unroll
        for (int j = 0; j < 4; ++j) acc[i][j] = (f32x4)0.0f;

    const unsigned short* ag = xb + (size_t)row0 * FEAT;
    const int srow = t >> 2;
    const int scol = (t & 3) * 8;

    for (int k0 = 0; k0 < FEAT; k0 += 32) {
#pragma unroll
        for (int i = 0; i < 2; ++i) {
            gload16(ag + (size_t)(i * 64 + srow) * FEAT + k0 + scol,
                    (char*)As + i * 4096 + t * 16);
            gload16(rt + (size_t)(i * 64 + srow) * FEAT + k0 + scol,
                    (char*)Bs + i * 4096 + t * 16);
        }
        __syncthreads();
        short8 a[4], b[4];
#pragma unroll
        for (int mi = 0; mi < 4; ++mi)
            a[mi] = *(const short8*)&As[(wm * 64 + mi * 16 + r16) * 32 + quad * 8];
#pragma unroll
        for (int ni = 0; ni < 4; ++ni)
            b[ni] = *(const short8*)&Bs[(wn * 64 + ni * 16 + r16) * 32 + quad * 8];
#pragma unroll
        for (int mi = 0; mi < 4; ++mi)
#pragma unroll
            for (int ni = 0; ni < 4; ++ni)
                acc[mi][ni] = __builtin_amdgcn_mfma_f32_16x16x32_bf16(
                    a[mi], b[ni], acc[mi][ni], 0, 0, 0);
        __syncthreads();
    }
    // logits -> LDS
#pragma unroll
    for (int mi = 0; mi < 4; ++mi) {
        const int r = wm * 64 + mi * 16 + quad * 4;
#pragma unroll
        for (int ni = 0; ni < 4; ++ni) {
            const int c = wn * 64 + ni * 16 + r16;
#pragma unroll
            for (int reg = 0; reg < 4; ++reg)
                lg[r + reg][c] = acc[mi][ni][reg];
        }
    }
    __syncthreads();
    // leaf probs: idx = i*256+t -> b = idx>>6 (wave-uniform), leaf = t&63
#pragma unroll 4
    for (int i = 0; i < 32; ++i) {
        const int idx  = i * 256 + t;
        const int b    = idx >> 6;
        const int leaf = idx & 63;
        float prod = 1.0f;
#pragma unroll
        for (int d = 0; d < 6; ++d) {
            const int n   = pnl[leaf * 6 + d];
            const int dir = pdl[leaf * 6 + d];
            if (n >= 0) {
                const float z0 = lg[b][n * 2];
                const float z1 = lg[b][n * 2 + 1];
                const float zd = dir ? z1 : z0;
                const float zo = dir ? z0 : z1;
                prod *= 1.0f / (1.0f + __expf(zo - zd));
            }
        }
        lp[(size_t)(row0 + b) * NLEAF + leaf] = prod;
    }
}

// ------------------------------ main GEMM ----------------------------------
// 256x256 tile, BK=64, 8 waves (2M x 4N), 2x double-buffered 128KB LDS,
// st_16x32 swizzle, 2 barriers/K-tile.
//
// R4 stage ledger (steady state, iteration kt):
//   P1: stage A0(kt+1), A1(kt+1)    (Abuf[kt+1] free since BAR-END of kt-1)
//   P2: stage B0(kt+2), B1(kt+2)    (Bbuf[kt] reads certified by BAR-A)
//   end: outstanding = [B(kt+1):4 (staged kt-1), A(kt+1):4 (staged kt P1),
//        B(kt+2):4 (staged kt P2)] = 12; vmcnt(4) drains B(kt+1)+A(kt+1),
//        leaves B(kt+2) flying. A(kt+1) now has a FULL K-tile of slack.
__global__ __launch_bounds__(512, 2) void leaf_gemm(
        const unsigned short* __restrict__ xb,   // [8192][1024] bf16
        const unsigned short* __restrict__ wt,   // [8192][1024] bf16 (leaf concat)
        const float* __restrict__ lp,            // [8192][64]
        const float* __restrict__ bias,          // [64][128]
        float* __restrict__ out) {               // [8192][8192]
    __shared__ __align__(16) char lds[134144];
    char* Abuf = lds;                              // 2 x 32KB
    char* Bbuf = lds + 65536;                      // 2 x 32KB
    float* lps = (float*)(lds + 131072);           // [2][256]
    float* bs  = (float*)(lds + 133120);           // [256]

    const int t = threadIdx.x;                     // 0..511

    // T1: bijective XCD swizzle (1024 wgs % 8 == 0)
    const int wg  = blockIdx.x;
    const int swz = (wg & 7) * 128 + (wg >> 3);
    const int by  = swz >> 5;                      // column tile 0..31
    const int bx  = swz & 31;                      // row tile 0..31
    const int row0 = bx * BM;
    const int col0 = by * BN;
    const int l0   = by * 2;                       // 2 leaves per 256-col tile

    // epilogue tables (drained before the stage ledger starts)
    {
        const int j = t >> 8, r = t & 255;
        lps[j * 256 + r] = lp[(size_t)(row0 + r) * NLEAF + l0 + j];
        if (t < 256) bs[t] = bias[l0 * LEAFD + t];
    }
    asm volatile("s_waitcnt vmcnt(0)" ::: "memory");  // keep vmcnt ledger clean

    // ---- staging geometry: inverse st_16x32 swizzle.
    int goff0, goff1;
    {
#pragma unroll
        for (int i = 0; i < 2; ++i) {
            const int q   = t + i * 512;           // 0..1023
            const int sub = q >> 6;                // subtile ordinal 0..15
            const int qq  = q & 63;
            const int r   = qq >> 2;               // 0..15
            const int cc  = (qq & 3) * 8;          // 0,8,16,24
            const int row = (sub >> 1) * 16 + r;
            const int col = (sub & 1) * 32 + (cc ^ ((r & 8) ? 16 : 0));
            const int off = row * FEAT + col;
            if (i == 0) goff0 = off; else goff1 = off;
        }
    }

    const unsigned short* Ag = xb + (size_t)row0 * FEAT;
    const unsigned short* Bg = wt + (size_t)col0 * FEAT;

#define STAGE(gbase, ldsbase, bufsel, h, kt)                                   \
    do {                                                                       \
        gload16(gbase + (h) * 131072 + (kt) * BK + goff0,                      \
                (ldsbase) + (bufsel) * 32768 + (h) * 16384 + t * 16);          \
        gload16(gbase + (h) * 131072 + (kt) * BK + goff1,                      \
                (ldsbase) + (bufsel) * 32768 + (h) * 16384 + 8192 + t * 16);   \
    } while (0)

    // wave / lane decomposition: 8 waves = 2 (M) x 4 (N); per-wave 128x64 out
    const int wv   = t >> 6;
    const int ln   = t & 63;
    const int wm   = wv >> 2;      // 0..1
    const int wn   = wv & 3;       // 0..3
    const int quad = ln >> 4;      // 0..3
    const int r16  = ln & 15;

    // swizzled per-lane fragment byte base within a subtile
    const int fb = r16 * 64 + ((quad * 8) ^ ((r16 & 8) << 1)) * 2;
    const char* Afb = Abuf + wm * 16384 + fb;   // + cur*32768 + mi*2048 + ks*1024
    const char* Bfb = Bbuf + wn * 8192 + fb;    // + cur*32768 + ni*2048 + ks*1024

    f32x4 acc[8][4];
#pragma unroll
    for (int i = 0; i < 8; ++i)
#pragma unroll
        for (int j = 0; j < 4; ++j) acc[i][j] = (f32x4)0.0f;

    // prologue: B(0), A(0), B(1); vmcnt(4) leaves B(1)'s 4 loads in flight
    STAGE(Bg, Bbuf, 0, 0, 0);
    STAGE(Bg, Bbuf, 0, 1, 0);
    STAGE(Ag, Abuf, 0, 0, 0);
    STAGE(Ag, Abuf, 0, 1, 0);
    STAGE(Bg, Bbuf, 1, 0, 1);
    STAGE(Bg, Bbuf, 1, 1, 1);
    asm volatile("s_waitcnt vmcnt(4)" ::: "memory");
    __builtin_amdgcn_s_barrier();

    short8 a[4][2], b01[2][2], b23[2][2];

#pragma unroll 2
    for (int kt = 0; kt < NT; ++kt) {
        const int cur = kt & 1;
        const char* Ac = Afb + cur * 32768;
        const char* Bc = Bfb + cur * 32768;

        // ---- P1: read a03 + ALL B fragments; stage A0+A1(kt+1); Q00
#pragma unroll
        for (int ni = 0; ni < 2; ++ni)
#pragma unroll
            for (int ks = 0; ks < 2; ++ks) {
                b01[ni][ks] = *(const short8*)(Bc + ni * 2048 + ks * 1024);
                b23[ni][ks] = *(const short8*)(Bc + (ni + 2) * 2048 + ks * 1024);
            }
#pragma unroll
        for (int mi = 0; mi < 4; ++mi)
#pragma unroll
            for (int ks = 0; ks < 2; ++ks)
                a[mi][ks] = *(const short8*)(Ac + mi * 2048 + ks * 1024);
        if (kt + 1 < NT) {
            STAGE(Ag, Abuf, (kt + 1) & 1, 0, kt + 1);
            STAGE(Ag, Abuf, (kt + 1) & 1, 1, kt + 1);
        }
        __builtin_amdgcn_s_setprio(1);
#pragma unroll
        for (int mi = 0; mi < 4; ++mi)
#pragma unroll
            for (int ni = 0; ni < 2; ++ni)
#pragma unroll
                for (int ks = 0; ks < 2; ++ks)
                    acc[mi][ni] = __builtin_amdgcn_mfma_f32_16x16x32_bf16(
                        a[mi][ks], b01[ni][ks], acc[mi][ni], 0, 0, 0);
        __builtin_amdgcn_s_setprio(0);
        // certify ALL waves' B-reads of tile kt before B(kt+2) staging
        asm volatile("s_waitcnt lgkmcnt(0)" ::: "memory");
        __builtin_amdgcn_s_barrier();               // BAR-A

        // ---- P2: stage B(kt+2); Q01; a47 re-read; Q10+Q11
        if (kt + 2 < NT) STAGE(Bg, Bbuf, kt & 1, 0, kt + 2);
        __builtin_amdgcn_s_setprio(1);
#pragma unroll
        for (int mi = 0; mi < 4; ++mi)
#pragma unroll
            for (int ni = 0; ni < 2; ++ni)
#pragma unroll
                for (int ks = 0; ks < 2; ++ks)
                    acc[mi][ni + 2] = __builtin_amdgcn_mfma_f32_16x16x32_bf16(
                        a[mi][ks], b23[ni][ks], acc[mi][ni + 2], 0, 0, 0);
        __builtin_amdgcn_s_setprio(0);
        // re-read a47 into a03's registers (WAR after Q01 consumed a03)
#pragma unroll
        for (int mi = 0; mi < 4; ++mi)
#pragma unroll
            for (int ks = 0; ks < 2; ++ks)
                a[mi][ks] = *(const short8*)(Ac + (mi + 4) * 2048 + ks * 1024);
        if (kt + 2 < NT) STAGE(Bg, Bbuf, kt & 1, 1, kt + 2);
        asm volatile("s_waitcnt lgkmcnt(0)" ::: "memory");
        __builtin_amdgcn_s_setprio(1);
#pragma unroll
        for (int mi = 0; mi < 4; ++mi)
#pragma unroll
            for (int ni = 0; ni < 2; ++ni)
#pragma unroll
                for (int ks = 0; ks < 2; ++ks)
                    acc[mi + 4][ni] = __builtin_amdgcn_mfma_f32_16x16x32_bf16(
                        a[mi][ks], b01[ni][ks], acc[mi + 4][ni], 0, 0, 0);
#pragma unroll
        for (int mi = 0; mi < 4; ++mi)
#pragma unroll
            for (int ni = 0; ni < 2; ++ni)
#pragma unroll
                for (int ks = 0; ks < 2; ++ks)
                    acc[mi + 4][ni + 2] = __builtin_amdgcn_mfma_f32_16x16x32_bf16(
                        a[mi][ks], b23[ni][ks], acc[mi + 4][ni + 2], 0, 0, 0);
        __builtin_amdgcn_s_setprio(0);

        // ---- end of K-tile: counted vmcnt + single re-sync barrier
        if (kt + 2 < NT) {
            asm volatile("s_waitcnt vmcnt(4)" ::: "memory");   // tile kt+1 arrived
        } else if (kt + 1 < NT) {
            asm volatile("s_waitcnt vmcnt(0)" ::: "memory");   // tail drain
        }
        __builtin_amdgcn_s_barrier();               // BAR-END
    }
#undef STAGE

    // epilogue: (acc + bias) * leaf_prob; ni innermost -> 4x64B back-to-back
    // per output row (256B contiguous merge window at TCC).
    const float* lpw = lps + (wn >> 1) * 256;
#pragma unroll
    for (int mi = 0; mi < 8; ++mi) {
        const int r = wm * 128 + mi * 16 + quad * 4;
#pragma unroll
        for (int reg = 0; reg < 4; ++reg) {
            const float lv = lpw[r + reg];
            float* orow = out + (size_t)(row0 + r + reg) * OUTD + col0 + wn * 64;
#pragma unroll
            for (int ni = 0; ni < 4; ++ni) {
                const int c = ni * 16 + r16;
                const float v = (acc[mi][ni][reg] + bs[wn * 64 + c]) * lv;
                __builtin_nontemporal_store(v, orow + c);
            }
        }
    }
}

// ------------------------------- launcher ----------------------------------

extern "C" void kernel_launch(void* const* d_in, const int* in_sizes, int n_in,
                              void* d_out, int out_size, void* d_ws, size_t ws_size,
                              hipStream_t stream) {
    const float* x    = (const float*)d_in[0];   // [8192][1024]
    const float* rw   = (const float*)d_in[1];   // [63][1024][2]
    const float* lw   = (const float*)d_in[2];   // [64][1024][128]
    const float* bias = (const float*)d_in[3];   // [64][128]
    const int*   pn   = (const int*)d_in[4];     // [64][6]
    const int*   pd   = (const int*)d_in[5];     // [64][6]
    float* out = (float*)d_out;

    char* ws = (char*)d_ws;
    unsigned short* xb  = (unsigned short*)(ws);               // 16 MB
    unsigned short* wt  = (unsigned short*)(ws + 16777216);    // 16 MB
    unsigned short* rt  = (unsigned short*)(ws + 33554432);    // 256 KB
    float*          lpv = (float*)(ws + 38010880);             // 2 MB

    cvt_x<<<8192, 256, 0, stream>>>(x, xb);
    cvt_lw<<<dim3(64, 32, 4), 256, 0, stream>>>(lw, wt);
    cvt_rw<<<512, 256, 0, stream>>>(rw, rt);
    routing_lp<<<64, 256, 0, stream>>>(xb, rt, pn, pd, lpv);
    leaf_gemm<<<1024, 512, 0, stream>>>(xb, wt, lpv, bias, out);
}